// Round 7
// baseline (1291.977 us; speedup 1.0000x reference)
//
#include <hip/hip_runtime.h>
#include <hip/hip_bf16.h>
#include <math.h>

#define N_NODES 50000
#define N_EDGES 800000
#define IN_DIM 50
#define HIDDEN 256
#define NCLS 121

// ---- workspace layout (float units) ----
// deg : [0, N_NODES)
// A   : [OFF_A, +N_NODES*HIDDEN)  (agg1 = first N_NODES*IN_DIM floats, then agg2)
// h   : [OFF_H, +N_NODES*HIDDEN)
// total 25,650,000 floats = 102.6 MB (ws_size >= 103.1 MB verified round 6)
#define OFF_A    (N_NODES)
#define OFF_H    (OFF_A + N_NODES * HIDDEN)

__device__ __forceinline__ int clampi(int v, int hi) {
    return v < 0 ? 0 : (v >= hi ? hi - 1 : v);
}

// ---------------- scatter for layer 1 (IN_DIM feats) ----------------
__global__ __launch_bounds__(256) void scatter1_r7(
    const float* __restrict__ x, const int* __restrict__ src,
    const int* __restrict__ dst, float* __restrict__ agg1,
    float* __restrict__ deg) {
    int e = blockIdx.x * 4 + (threadIdx.x >> 6);
    int lane = threadIdx.x & 63;
    int s = clampi(src[e], N_NODES);
    int d = clampi(dst[e], N_NODES);
    if (lane < IN_DIM)
        atomicAdd(&agg1[d * IN_DIM + lane], x[s * IN_DIM + lane]);
    if (lane == 63)
        atomicAdd(&deg[d], 1.0f);
}

// ---------------- layer 1: 8 nodes/block, 256 threads ----------------
__global__ __launch_bounds__(256) void layer1_r7(
    const float* __restrict__ x, const float* __restrict__ agg1,
    const float* __restrict__ deg,
    const float* __restrict__ w1l, const float* __restrict__ b1,
    const float* __restrict__ w1r, const float* __restrict__ wl1,
    const float* __restrict__ bl1, float* __restrict__ h) {
    __shared__ float xs[8][IN_DIM];
    __shared__ float ms[8][IN_DIM];
    __shared__ float red[8][HIDDEN];
    __shared__ float rdeg[8];

    int base = blockIdx.x * 8;
    int tid = threadIdx.x;
    if (tid < 8) rdeg[tid] = 1.0f / fmaxf(deg[base + tid], 1.0f);
    for (int idx = tid; idx < 8 * IN_DIM; idx += 256) {
        int n = idx / IN_DIM, f = idx % IN_DIM;
        xs[n][f] = x[(base + n) * IN_DIM + f];
        ms[n][f] = agg1[(base + n) * IN_DIM + f];  // un-normalized sum
    }
    __syncthreads();

    int j = tid;  // hidden column
    float accA[8] = {0}, accB[8] = {0}, accC[8] = {0};
    for (int f = 0; f < IN_DIM; ++f) {
        float wa = w1l[f * HIDDEN + j];
        float wb = w1r[f * HIDDEN + j];
        float wc = wl1[f * HIDDEN + j];
#pragma unroll
        for (int n = 0; n < 8; ++n) {
            accA[n] += ms[n][f] * wa;
            accB[n] += xs[n][f] * wb;
            accC[n] += xs[n][f] * wc;
        }
    }
    float bj = b1[j];
    float blj = bl1[j];
    float out1[8];
#pragma unroll
    for (int n = 0; n < 8; ++n) {
        out1[n] = accA[n] * rdeg[n] + bj + accB[n];
        red[n][j] = out1[n] * out1[n];
    }
    __syncthreads();
    for (int stride = 128; stride > 0; stride >>= 1) {
        if (j < stride) {
#pragma unroll
            for (int n = 0; n < 8; ++n) red[n][j] += red[n][j + stride];
        }
        __syncthreads();
    }
#pragma unroll
    for (int n = 0; n < 8; ++n) {
        float rn = 1.0f / fmaxf(sqrtf(red[n][0]), 1e-12f);
        float z = out1[n] * rn + accC[n] + blj;
        h[(base + n) * HIDDEN + j] = z > 0.0f ? z : expm1f(z);
    }
}

// ---------------- scatter for layer 2 (HIDDEN feats) ----------------
__global__ __launch_bounds__(256) void scatter2_r7(
    const float* __restrict__ h, const int* __restrict__ src,
    const int* __restrict__ dst, float* __restrict__ agg2) {
    int e = blockIdx.x;
    int k = threadIdx.x;
    int s = clampi(src[e], N_NODES);
    int d = clampi(dst[e], N_NODES);
    atomicAdd(&agg2[d * HIDDEN + k], h[s * HIDDEN + k]);
}

// ---------------- layer 2: 8 nodes/block, 128 threads, fp32 output ------
__global__ __launch_bounds__(128) void layer2_r7(
    const float* __restrict__ h, const float* __restrict__ agg2,
    const float* __restrict__ deg,
    const float* __restrict__ w2l, const float* __restrict__ b2,
    const float* __restrict__ w2r, const float* __restrict__ wl2,
    const float* __restrict__ bl2, float* __restrict__ out) {
    __shared__ float hs[8][HIDDEN];
    __shared__ float ms[8][HIDDEN];
    __shared__ float red[8][128];
    __shared__ float rdeg[8];

    int base = blockIdx.x * 8;
    int tid = threadIdx.x;
    if (tid < 8) rdeg[tid] = 1.0f / fmaxf(deg[base + tid], 1.0f);
    for (int idx = tid; idx < 8 * HIDDEN; idx += 128) {
        int n = idx >> 8, k = idx & 255;
        hs[n][k] = h[(base + n) * HIDDEN + k];
        ms[n][k] = agg2[(base + n) * HIDDEN + k];
    }
    __syncthreads();

    int j = tid;  // class column (121 active)
    float accA[8] = {0}, accB[8] = {0}, accC[8] = {0};
    if (j < NCLS) {
        for (int k = 0; k < HIDDEN; ++k) {
            float wa = w2l[k * NCLS + j];
            float wb = w2r[k * NCLS + j];
            float wc = wl2[k * NCLS + j];
#pragma unroll
            for (int n = 0; n < 8; ++n) {
                accA[n] += ms[n][k] * wa;
                accB[n] += hs[n][k] * wb;
                accC[n] += hs[n][k] * wc;
            }
        }
    }
    float bj = (j < NCLS) ? b2[j] : 0.0f;
    float blj = (j < NCLS) ? bl2[j] : 0.0f;
    float out2[8];
#pragma unroll
    for (int n = 0; n < 8; ++n) {
        out2[n] = accA[n] * rdeg[n] + bj + accB[n];
        red[n][j] = (j < NCLS) ? out2[n] * out2[n] : 0.0f;
    }
    __syncthreads();
    for (int stride = 64; stride > 0; stride >>= 1) {
        if (j < stride) {
#pragma unroll
            for (int n = 0; n < 8; ++n) red[n][j] += red[n][j + stride];
        }
        __syncthreads();
    }
    if (j < NCLS) {
#pragma unroll
        for (int n = 0; n < 8; ++n) {
            float rn = 1.0f / fmaxf(sqrtf(red[n][0]), 1e-12f);
            out[(base + n) * NCLS + j] = out2[n] * rn + accC[n] + blj;  // fp32 write
        }
    }
}

extern "C" void kernel_launch(void* const* d_in, const int* in_sizes, int n_in,
                              void* d_out, int out_size, void* d_ws, size_t ws_size,
                              hipStream_t stream) {
    const float* x   = (const float*)d_in[0];
    const int*   ei  = (const int*)d_in[1];
    const float* w1l = (const float*)d_in[2];
    const float* b1  = (const float*)d_in[3];
    const float* w1r = (const float*)d_in[4];
    const float* wl1 = (const float*)d_in[5];
    const float* bl1 = (const float*)d_in[6];
    const float* w2l = (const float*)d_in[7];
    const float* b2  = (const float*)d_in[8];
    const float* w2r = (const float*)d_in[9];
    const float* wl2 = (const float*)d_in[10];
    const float* bl2 = (const float*)d_in[11];
    float* out = (float*)d_out;   // reference output dtype is float32

    const int* src = ei;
    const int* dst = ei + N_EDGES;

    float* ws  = (float*)d_ws;
    float* deg = ws;
    float* A   = ws + OFF_A;   // agg1 first, then reused as agg2
    float* h   = ws + OFF_H;

    // zero deg + agg1 (contiguous prefix)
    hipMemsetAsync(deg, 0, (size_t)(N_NODES + N_NODES * IN_DIM) * sizeof(float), stream);

    scatter1_r7<<<N_EDGES / 4, 256, 0, stream>>>(x, src, dst, A, deg);
    layer1_r7<<<N_NODES / 8, 256, 0, stream>>>(x, A, deg, w1l, b1, w1r, wl1, bl1, h);

    // layer1 consumed agg1; re-zero whole A region for agg2
    hipMemsetAsync(A, 0, (size_t)(N_NODES * HIDDEN) * sizeof(float), stream);

    scatter2_r7<<<N_EDGES, 256, 0, stream>>>(h, src, dst, A);
    layer2_r7<<<N_NODES / 8, 128, 0, stream>>>(h, A, deg, w2l, b2, w2r, wl2, bl2, out);
}

// Round 8
// 756.894 us; speedup vs baseline: 1.7069x; 1.7069x over previous
//
#include <hip/hip_runtime.h>
#include <hip/hip_bf16.h>
#include <math.h>

#define N_NODES 50000
#define N_EDGES 800000
#define IN_DIM 50
#define HIDDEN 256
#define NCLS 121
#define PSTR 128  // padded stride for p (121 -> 128, 512B-aligned rows)

// ---- workspace layout (4-byte units) ----
// degi : int [0, 50000)
// off  : int [50048, +50001)
// cur  : int [100112, +50000)
// csr  : int [150160, +800000)   (src ids grouped by dst)
// h    : float [950272, +12800000)
// p    : float [13750272, +6400000)   = h @ w2_l, padded to 128
// total 20,150,272 * 4B = 80.6 MB  (ws >= 103.1 MB verified round 6)
#define OFF_OFF  50048
#define OFF_CUR  100112
#define OFF_CSR  150160
#define OFF_H    950272
#define OFF_P    13750272

__device__ __forceinline__ int clampi(int v, int hi) {
    return v < 0 ? 0 : (v >= hi ? hi - 1 : v);
}

// ---------------- CSR build ----------------
__global__ __launch_bounds__(256) void degcount_r8(const int* __restrict__ dst,
                                                   int* __restrict__ degi) {
    int e = blockIdx.x * 256 + threadIdx.x;
    if (e < N_EDGES) atomicAdd(&degi[clampi(dst[e], N_NODES)], 1);
}

// single-block exclusive scan over 50000 degrees -> off[0..N], cur copy
__global__ __launch_bounds__(256) void scan_r8(const int* __restrict__ degi,
                                               int* __restrict__ off,
                                               int* __restrict__ cur) {
    __shared__ int part[256];
    const int CH = (N_NODES + 255) / 256;  // 196
    int t = threadIdx.x;
    int begin = t * CH;
    int end = begin + CH < N_NODES ? begin + CH : N_NODES;
    int s = 0;
    for (int i = begin; i < end; ++i) s += degi[i];
    part[t] = s;
    __syncthreads();
    for (int d = 1; d < 256; d <<= 1) {
        int u = (t >= d) ? part[t - d] : 0;
        __syncthreads();
        part[t] += u;
        __syncthreads();
    }
    int run = part[t] - s;  // exclusive prefix of this chunk
    for (int i = begin; i < end; ++i) {
        off[i] = run;
        cur[i] = run;
        run += degi[i];
    }
    if (end == N_NODES) off[N_NODES] = run;
}

__global__ __launch_bounds__(256) void csrfill_r8(const int* __restrict__ src,
                                                  const int* __restrict__ dst,
                                                  int* __restrict__ cur,
                                                  int* __restrict__ csr) {
    int e = blockIdx.x * 256 + threadIdx.x;
    if (e >= N_EDGES) return;
    int d = clampi(dst[e], N_NODES);
    int pos = atomicAdd(&cur[d], 1);
    csr[pos] = clampi(src[e], N_NODES);
}

// ---------------- layer 1 (fused CSR aggregation): 8 nodes, 256 thr ----------
__global__ __launch_bounds__(256) void layer1_r8(
    const float* __restrict__ x, const int* __restrict__ off,
    const int* __restrict__ csr, const int* __restrict__ degi,
    const float* __restrict__ w1l, const float* __restrict__ b1,
    const float* __restrict__ w1r, const float* __restrict__ wl1,
    const float* __restrict__ bl1, float* __restrict__ h) {
    __shared__ float xs[8][IN_DIM];
    __shared__ float ms[8][IN_DIM];
    __shared__ float red[8][HIDDEN];
    __shared__ float rdeg[8];

    int base = blockIdx.x * 8;
    int tid = threadIdx.x;
    int wave = tid >> 6, lane = tid & 63;

    if (tid < 8) rdeg[tid] = 1.0f / fmaxf((float)degi[base + tid], 1.0f);
    for (int idx = tid; idx < 8 * IN_DIM; idx += 256) {
        int n = idx / IN_DIM, f = idx % IN_DIM;
        xs[n][f] = x[(base + n) * IN_DIM + f];
    }
    // gather-aggregate: wave w handles nodes 2w, 2w+1
    for (int r = 0; r < 2; ++r) {
        int n = wave * 2 + r;
        int node = base + n;
        float acc = 0.0f;
        int e1 = off[node + 1];
        for (int e = off[node]; e < e1; ++e) {
            int s = csr[e];
            if (lane < IN_DIM) acc += x[s * IN_DIM + lane];
        }
        if (lane < IN_DIM) ms[n][lane] = acc;
    }
    __syncthreads();

    int j = tid;  // hidden column
    float accA[8] = {0}, accB[8] = {0}, accC[8] = {0};
    for (int f = 0; f < IN_DIM; ++f) {
        float wa = w1l[f * HIDDEN + j];
        float wb = w1r[f * HIDDEN + j];
        float wc = wl1[f * HIDDEN + j];
#pragma unroll
        for (int n = 0; n < 8; ++n) {
            accA[n] += ms[n][f] * wa;
            accB[n] += xs[n][f] * wb;
            accC[n] += xs[n][f] * wc;
        }
    }
    float bj = b1[j];
    float blj = bl1[j];
    float out1[8];
#pragma unroll
    for (int n = 0; n < 8; ++n) {
        out1[n] = accA[n] * rdeg[n] + bj + accB[n];
        red[n][j] = out1[n] * out1[n];
    }
    __syncthreads();
    for (int stride = 128; stride > 0; stride >>= 1) {
        if (j < stride) {
#pragma unroll
            for (int n = 0; n < 8; ++n) red[n][j] += red[n][j + stride];
        }
        __syncthreads();
    }
#pragma unroll
    for (int n = 0; n < 8; ++n) {
        float rn = 1.0f / fmaxf(sqrtf(red[n][0]), 1e-12f);
        float z = out1[n] * rn + accC[n] + blj;
        h[(base + n) * HIDDEN + j] = z > 0.0f ? z : expm1f(z);
    }
}

// ---------------- p = h @ w2_l  (project BEFORE aggregating) ----------------
__global__ __launch_bounds__(128) void project2_r8(
    const float* __restrict__ h, const float* __restrict__ w2l,
    float* __restrict__ p) {
    __shared__ float hs[8][HIDDEN];
    int base = blockIdx.x * 8;
    int tid = threadIdx.x;
    for (int idx = tid; idx < 8 * HIDDEN; idx += 128) {
        int n = idx >> 8, k = idx & 255;
        hs[n][k] = h[(base + n) * HIDDEN + k];
    }
    __syncthreads();
    int j = tid;
    if (j >= NCLS) return;
    float acc[8] = {0};
    for (int k = 0; k < HIDDEN; ++k) {
        float w = w2l[k * NCLS + j];
#pragma unroll
        for (int n = 0; n < 8; ++n) acc[n] += hs[n][k] * w;
    }
#pragma unroll
    for (int n = 0; n < 8; ++n) p[(base + n) * PSTR + j] = acc[n];
}

// ---------------- layer 2 final (fused CSR gather of p): 8 nodes, 128 thr ---
__global__ __launch_bounds__(128) void layer2_r8(
    const float* __restrict__ h, const float* __restrict__ p,
    const int* __restrict__ off, const int* __restrict__ csr,
    const int* __restrict__ degi,
    const float* __restrict__ b2, const float* __restrict__ w2r,
    const float* __restrict__ wl2, const float* __restrict__ bl2,
    float* __restrict__ out) {
    __shared__ float hs[8][HIDDEN];
    __shared__ float mp[8][NCLS];
    __shared__ float red[8][128];
    __shared__ float rdeg[8];

    int base = blockIdx.x * 8;
    int tid = threadIdx.x;
    if (tid < 8) rdeg[tid] = 1.0f / fmaxf((float)degi[base + tid], 1.0f);
    for (int idx = tid; idx < 8 * HIDDEN; idx += 128) {
        int n = idx >> 8, k = idx & 255;
        hs[n][k] = h[(base + n) * HIDDEN + k];
    }
    // gather-aggregate p over in-edges; whole block per node, serial nodes
    for (int n = 0; n < 8; ++n) {
        int node = base + n;
        float acc = 0.0f;
        int e1 = off[node + 1];
        for (int e = off[node]; e < e1; ++e) {
            int s = csr[e];
            if (tid < NCLS) acc += p[s * PSTR + tid];
        }
        if (tid < NCLS) mp[n][tid] = acc;
    }
    __syncthreads();

    int j = tid;
    float accB[8] = {0}, accC[8] = {0};
    if (j < NCLS) {
        for (int k = 0; k < HIDDEN; ++k) {
            float wb = w2r[k * NCLS + j];
            float wc = wl2[k * NCLS + j];
#pragma unroll
            for (int n = 0; n < 8; ++n) {
                accB[n] += hs[n][k] * wb;
                accC[n] += hs[n][k] * wc;
            }
        }
    }
    float bj = (j < NCLS) ? b2[j] : 0.0f;
    float blj = (j < NCLS) ? bl2[j] : 0.0f;
    float out2[8];
#pragma unroll
    for (int n = 0; n < 8; ++n) {
        out2[n] = (j < NCLS) ? (mp[n][j] * rdeg[n] + bj + accB[n]) : 0.0f;
        red[n][j] = out2[n] * out2[n];
    }
    __syncthreads();
    for (int stride = 64; stride > 0; stride >>= 1) {
        if (j < stride) {
#pragma unroll
            for (int n = 0; n < 8; ++n) red[n][j] += red[n][j + stride];
        }
        __syncthreads();
    }
    if (j < NCLS) {
#pragma unroll
        for (int n = 0; n < 8; ++n) {
            float rn = 1.0f / fmaxf(sqrtf(red[n][0]), 1e-12f);
            out[(base + n) * NCLS + j] = out2[n] * rn + accC[n] + blj;
        }
    }
}

extern "C" void kernel_launch(void* const* d_in, const int* in_sizes, int n_in,
                              void* d_out, int out_size, void* d_ws, size_t ws_size,
                              hipStream_t stream) {
    const float* x   = (const float*)d_in[0];
    const int*   ei  = (const int*)d_in[1];
    const float* w1l = (const float*)d_in[2];
    const float* b1  = (const float*)d_in[3];
    const float* w1r = (const float*)d_in[4];
    const float* wl1 = (const float*)d_in[5];
    const float* bl1 = (const float*)d_in[6];
    const float* w2l = (const float*)d_in[7];
    const float* b2  = (const float*)d_in[8];
    const float* w2r = (const float*)d_in[9];
    const float* wl2 = (const float*)d_in[10];
    const float* bl2 = (const float*)d_in[11];
    float* out = (float*)d_out;

    const int* src = ei;
    const int* dst = ei + N_EDGES;

    int*   wsI  = (int*)d_ws;
    float* wsF  = (float*)d_ws;
    int*   degi = wsI;
    int*   off  = wsI + OFF_OFF;
    int*   cur  = wsI + OFF_CUR;
    int*   csr  = wsI + OFF_CSR;
    float* h    = wsF + OFF_H;
    float* p    = wsF + OFF_P;

    hipMemsetAsync(degi, 0, (size_t)N_NODES * sizeof(int), stream);

    degcount_r8<<<(N_EDGES + 255) / 256, 256, 0, stream>>>(dst, degi);
    scan_r8<<<1, 256, 0, stream>>>(degi, off, cur);
    csrfill_r8<<<(N_EDGES + 255) / 256, 256, 0, stream>>>(src, dst, cur, csr);

    layer1_r8<<<N_NODES / 8, 256, 0, stream>>>(x, off, csr, degi,
                                               w1l, b1, w1r, wl1, bl1, h);
    project2_r8<<<N_NODES / 8, 128, 0, stream>>>(h, w2l, p);
    layer2_r8<<<N_NODES / 8, 128, 0, stream>>>(h, p, off, csr, degi,
                                               b2, w2r, wl2, bl2, out);
}

// Round 9
// 656.935 us; speedup vs baseline: 1.9667x; 1.1522x over previous
//
#include <hip/hip_runtime.h>
#include <hip/hip_bf16.h>
#include <math.h>

#define N_NODES 50000
#define N_EDGES 800000
#define IN_DIM 50
#define HIDDEN 256
#define NCLS 121
#define PSTR 128  // padded stride for p rows (512B)

// ---- workspace layout (4-byte units) ----
#define OFF_OFF  50048
#define OFF_CUR  100112
#define OFF_CSR  150160
#define OFF_H    950272
#define OFF_P    13750272

__device__ __forceinline__ int clampi(int v, int hi) {
    return v < 0 ? 0 : (v >= hi ? hi - 1 : v);
}

// ---------------- CSR build ----------------
__global__ __launch_bounds__(256) void degcount_r9(const int* __restrict__ dst,
                                                   int* __restrict__ degi) {
    int e = blockIdx.x * 256 + threadIdx.x;
    if (e < N_EDGES) atomicAdd(&degi[clampi(dst[e], N_NODES)], 1);
}

__global__ __launch_bounds__(256) void scan_r9(const int* __restrict__ degi,
                                               int* __restrict__ off,
                                               int* __restrict__ cur) {
    __shared__ int part[256];
    const int CH = (N_NODES + 255) / 256;  // 196
    int t = threadIdx.x;
    int begin = t * CH;
    int end = begin + CH < N_NODES ? begin + CH : N_NODES;
    int s = 0;
    for (int i = begin; i < end; ++i) s += degi[i];
    part[t] = s;
    __syncthreads();
    for (int d = 1; d < 256; d <<= 1) {
        int u = (t >= d) ? part[t - d] : 0;
        __syncthreads();
        part[t] += u;
        __syncthreads();
    }
    int run = part[t] - s;
    for (int i = begin; i < end; ++i) {
        off[i] = run;
        cur[i] = run;
        run += degi[i];
    }
    if (end == N_NODES) off[N_NODES] = run;
}

__global__ __launch_bounds__(256) void csrfill_r9(const int* __restrict__ src,
                                                  const int* __restrict__ dst,
                                                  int* __restrict__ cur,
                                                  int* __restrict__ csr) {
    int e = blockIdx.x * 256 + threadIdx.x;
    if (e >= N_EDGES) return;
    int d = clampi(dst[e], N_NODES);
    int pos = atomicAdd(&cur[d], 1);
    csr[pos] = clampi(src[e], N_NODES);
}

// ---------------- layer 1 (fused CSR gather, 4-way MLP): 8 nodes, 256 thr ----
__global__ __launch_bounds__(256) void layer1_r9(
    const float* __restrict__ x, const int* __restrict__ off,
    const int* __restrict__ csr, const int* __restrict__ degi,
    const float* __restrict__ w1l, const float* __restrict__ b1,
    const float* __restrict__ w1r, const float* __restrict__ wl1,
    const float* __restrict__ bl1, float* __restrict__ h) {
    __shared__ float xs[8][IN_DIM];
    __shared__ float ms[8][IN_DIM];
    __shared__ float red[8][HIDDEN];
    __shared__ float rdeg[8];

    int base = blockIdx.x * 8;
    int tid = threadIdx.x;
    int wave = tid >> 6, lane = tid & 63;

    if (tid < 8) rdeg[tid] = 1.0f / fmaxf((float)degi[base + tid], 1.0f);
    for (int idx = tid; idx < 8 * IN_DIM; idx += 256) {
        int n = idx / IN_DIM, f = idx % IN_DIM;
        xs[n][f] = x[(base + n) * IN_DIM + f];
    }
    // gather-aggregate with 4 independent accumulators (MLP)
    for (int r = 0; r < 2; ++r) {
        int n = wave * 2 + r;
        int node = base + n;
        int e0 = off[node], e1 = off[node + 1];
        float a0 = 0, a1 = 0, a2 = 0, a3 = 0;
        int e = e0;
        for (; e + 4 <= e1; e += 4) {
            int s0 = csr[e], s1 = csr[e + 1], s2 = csr[e + 2], s3 = csr[e + 3];
            if (lane < IN_DIM) {
                a0 += x[s0 * IN_DIM + lane];
                a1 += x[s1 * IN_DIM + lane];
                a2 += x[s2 * IN_DIM + lane];
                a3 += x[s3 * IN_DIM + lane];
            }
        }
        for (; e < e1; ++e)
            if (lane < IN_DIM) a0 += x[csr[e] * IN_DIM + lane];
        if (lane < IN_DIM) ms[n][lane] = (a0 + a1) + (a2 + a3);
    }
    __syncthreads();

    int j = tid;  // hidden column
    float accA[8] = {0}, accB[8] = {0}, accC[8] = {0};
    for (int f = 0; f < IN_DIM; ++f) {
        float wa = w1l[f * HIDDEN + j];
        float wb = w1r[f * HIDDEN + j];
        float wc = wl1[f * HIDDEN + j];
#pragma unroll
        for (int n = 0; n < 8; ++n) {
            accA[n] += ms[n][f] * wa;
            accB[n] += xs[n][f] * wb;
            accC[n] += xs[n][f] * wc;
        }
    }
    float bj = b1[j];
    float blj = bl1[j];
    float out1[8];
#pragma unroll
    for (int n = 0; n < 8; ++n) {
        out1[n] = accA[n] * rdeg[n] + bj + accB[n];
        red[n][j] = out1[n] * out1[n];
    }
    __syncthreads();
    for (int stride = 128; stride > 0; stride >>= 1) {
        if (j < stride) {
#pragma unroll
            for (int n = 0; n < 8; ++n) red[n][j] += red[n][j + stride];
        }
        __syncthreads();
    }
#pragma unroll
    for (int n = 0; n < 8; ++n) {
        float rn = 1.0f / fmaxf(sqrtf(red[n][0]), 1e-12f);
        float z = out1[n] * rn + accC[n] + blj;
        h[(base + n) * HIDDEN + j] = z > 0.0f ? z : expm1f(z);
    }
}

// ---------------- p = h @ w2_l ----------------
__global__ __launch_bounds__(128) void project2_r9(
    const float* __restrict__ h, const float* __restrict__ w2l,
    float* __restrict__ p) {
    __shared__ float hs[8][HIDDEN];
    int base = blockIdx.x * 8;
    int tid = threadIdx.x;
    for (int idx = tid; idx < 8 * HIDDEN; idx += 128) {
        int n = idx >> 8, k = idx & 255;
        hs[n][k] = h[(base + n) * HIDDEN + k];
    }
    __syncthreads();
    int j = tid;
    if (j >= NCLS) return;
    float acc[8] = {0};
    for (int k = 0; k < HIDDEN; ++k) {
        float w = w2l[k * NCLS + j];
#pragma unroll
        for (int n = 0; n < 8; ++n) acc[n] += hs[n][k] * w;
    }
#pragma unroll
    for (int n = 0; n < 8; ++n) p[(base + n) * PSTR + j] = acc[n];
}

// ---------------- layer 2 final (4-way MLP gather): 8 nodes, 128 thr --------
__global__ __launch_bounds__(128) void layer2_r9(
    const float* __restrict__ h, const float* __restrict__ p,
    const int* __restrict__ off, const int* __restrict__ csr,
    const int* __restrict__ degi,
    const float* __restrict__ b2, const float* __restrict__ w2r,
    const float* __restrict__ wl2, const float* __restrict__ bl2,
    float* __restrict__ out) {
    __shared__ float hs[8][HIDDEN];
    __shared__ float mp[8][NCLS];
    __shared__ float red[8][128];
    __shared__ float rdeg[8];

    int base = blockIdx.x * 8;
    int tid = threadIdx.x;
    if (tid < 8) rdeg[tid] = 1.0f / fmaxf((float)degi[base + tid], 1.0f);
    for (int idx = tid; idx < 8 * HIDDEN; idx += 128) {
        int n = idx >> 8, k = idx & 255;
        hs[n][k] = h[(base + n) * HIDDEN + k];
    }
    // gather-aggregate p with 4 independent accumulators
    for (int n = 0; n < 8; ++n) {
        int node = base + n;
        int e0 = off[node], e1 = off[node + 1];
        if (tid < NCLS) {
            float a0 = 0, a1 = 0, a2 = 0, a3 = 0;
            int e = e0;
            for (; e + 4 <= e1; e += 4) {
                int s0 = csr[e], s1 = csr[e + 1];
                int s2 = csr[e + 2], s3 = csr[e + 3];
                a0 += p[s0 * PSTR + tid];
                a1 += p[s1 * PSTR + tid];
                a2 += p[s2 * PSTR + tid];
                a3 += p[s3 * PSTR + tid];
            }
            for (; e < e1; ++e) a0 += p[csr[e] * PSTR + tid];
            mp[n][tid] = (a0 + a1) + (a2 + a3);
        }
    }
    __syncthreads();

    int j = tid;
    float accB[8] = {0}, accC[8] = {0};
    if (j < NCLS) {
        for (int k = 0; k < HIDDEN; ++k) {
            float wb = w2r[k * NCLS + j];
            float wc = wl2[k * NCLS + j];
#pragma unroll
            for (int n = 0; n < 8; ++n) {
                accB[n] += hs[n][k] * wb;
                accC[n] += hs[n][k] * wc;
            }
        }
    }
    float bj = (j < NCLS) ? b2[j] : 0.0f;
    float blj = (j < NCLS) ? bl2[j] : 0.0f;
    float out2[8];
#pragma unroll
    for (int n = 0; n < 8; ++n) {
        out2[n] = (j < NCLS) ? (mp[n][j] * rdeg[n] + bj + accB[n]) : 0.0f;
        red[n][j] = out2[n] * out2[n];
    }
    __syncthreads();
    for (int stride = 64; stride > 0; stride >>= 1) {
        if (j < stride) {
#pragma unroll
            for (int n = 0; n < 8; ++n) red[n][j] += red[n][j + stride];
        }
        __syncthreads();
    }
    if (j < NCLS) {
#pragma unroll
        for (int n = 0; n < 8; ++n) {
            float rn = 1.0f / fmaxf(sqrtf(red[n][0]), 1e-12f);
            out[(base + n) * NCLS + j] = out2[n] * rn + accC[n] + blj;
        }
    }
}

extern "C" void kernel_launch(void* const* d_in, const int* in_sizes, int n_in,
                              void* d_out, int out_size, void* d_ws, size_t ws_size,
                              hipStream_t stream) {
    const float* x   = (const float*)d_in[0];
    const int*   ei  = (const int*)d_in[1];
    const float* w1l = (const float*)d_in[2];
    const float* b1  = (const float*)d_in[3];
    const float* w1r = (const float*)d_in[4];
    const float* wl1 = (const float*)d_in[5];
    const float* bl1 = (const float*)d_in[6];
    const float* w2l = (const float*)d_in[7];
    const float* b2  = (const float*)d_in[8];
    const float* w2r = (const float*)d_in[9];
    const float* wl2 = (const float*)d_in[10];
    const float* bl2 = (const float*)d_in[11];
    float* out = (float*)d_out;

    const int* src = ei;
    const int* dst = ei + N_EDGES;

    int*   wsI  = (int*)d_ws;
    float* wsF  = (float*)d_ws;
    int*   degi = wsI;
    int*   off  = wsI + OFF_OFF;
    int*   cur  = wsI + OFF_CUR;
    int*   csr  = wsI + OFF_CSR;
    float* h    = wsF + OFF_H;
    float* p    = wsF + OFF_P;

    hipMemsetAsync(degi, 0, (size_t)N_NODES * sizeof(int), stream);

    degcount_r9<<<(N_EDGES + 255) / 256, 256, 0, stream>>>(dst, degi);
    scan_r9<<<1, 256, 0, stream>>>(degi, off, cur);
    csrfill_r9<<<(N_EDGES + 255) / 256, 256, 0, stream>>>(src, dst, cur, csr);

    layer1_r9<<<N_NODES / 8, 256, 0, stream>>>(x, off, csr, degi,
                                               w1l, b1, w1r, wl1, bl1, h);
    project2_r9<<<N_NODES / 8, 128, 0, stream>>>(h, w2l, p);
    layer2_r9<<<N_NODES / 8, 128, 0, stream>>>(h, p, off, csr, degi,
                                               b2, w2r, wl2, bl2, out);
}

// Round 10
// 636.836 us; speedup vs baseline: 2.0287x; 1.0316x over previous
//
#include <hip/hip_runtime.h>
#include <hip/hip_bf16.h>
#include <math.h>

typedef __hip_bfloat16 bf16;

#define N_NODES 50000
#define N_EDGES 800000
#define IN_DIM 50
#define HIDDEN 256
#define NCLS 121
#define PSTR 128  // padded stride for p rows (128 bf16 = 256 B)

// ---- workspace layout (4-byte units) ----
// degi : int   [0, +50000)
// off  : int   [50048, +50001)
// cur  : int   [100112, +50000)
// csr  : int   [150160, +800000)
// h    : float [950272, +12800000)
// pb   : bf16  [13750272*4B, 50000*128 bf16 = 12.8 MB -> 3200000 units)
// xb   : bf16  [16950272*4B, 50000*50 bf16 = 5 MB -> 1250000 units)
// total ~72.8 MB (ws >= 103.1 MB verified)
#define OFF_OFF  50048
#define OFF_CUR  100112
#define OFF_CSR  150160
#define OFF_H    950272
#define OFF_PB   13750272
#define OFF_XB   16950272

__device__ __forceinline__ int clampi(int v, int hi) {
    return v < 0 ? 0 : (v >= hi ? hi - 1 : v);
}

// ---------------- x -> bf16 copy (gather operand) ----------------
__global__ __launch_bounds__(256) void convx_r10(const float* __restrict__ x,
                                                 bf16* __restrict__ xb) {
    int i = blockIdx.x * 256 + threadIdx.x;
    if (i < N_NODES * IN_DIM) xb[i] = __float2bfloat16(x[i]);
}

// ---------------- CSR build ----------------
__global__ __launch_bounds__(256) void degcount_r10(const int* __restrict__ dst,
                                                    int* __restrict__ degi) {
    int e = blockIdx.x * 256 + threadIdx.x;
    if (e < N_EDGES) atomicAdd(&degi[clampi(dst[e], N_NODES)], 1);
}

__global__ __launch_bounds__(256) void scan_r10(const int* __restrict__ degi,
                                                int* __restrict__ off,
                                                int* __restrict__ cur) {
    __shared__ int part[256];
    const int CH = (N_NODES + 255) / 256;
    int t = threadIdx.x;
    int begin = t * CH;
    int end = begin + CH < N_NODES ? begin + CH : N_NODES;
    int s = 0;
    for (int i = begin; i < end; ++i) s += degi[i];
    part[t] = s;
    __syncthreads();
    for (int d = 1; d < 256; d <<= 1) {
        int u = (t >= d) ? part[t - d] : 0;
        __syncthreads();
        part[t] += u;
        __syncthreads();
    }
    int run = part[t] - s;
    for (int i = begin; i < end; ++i) {
        off[i] = run;
        cur[i] = run;
        run += degi[i];
    }
    if (end == N_NODES) off[N_NODES] = run;
}

__global__ __launch_bounds__(256) void csrfill_r10(const int* __restrict__ src,
                                                   const int* __restrict__ dst,
                                                   int* __restrict__ cur,
                                                   int* __restrict__ csr) {
    int e = blockIdx.x * 256 + threadIdx.x;
    if (e >= N_EDGES) return;
    int d = clampi(dst[e], N_NODES);
    int pos = atomicAdd(&cur[d], 1);
    csr[pos] = clampi(src[e], N_NODES);
}

// ---------------- layer 1 (bf16 gather, 4-way MLP): 8 nodes, 256 thr --------
__global__ __launch_bounds__(256) void layer1_r10(
    const float* __restrict__ x, const bf16* __restrict__ xb,
    const int* __restrict__ off, const int* __restrict__ csr,
    const int* __restrict__ degi,
    const float* __restrict__ w1l, const float* __restrict__ b1,
    const float* __restrict__ w1r, const float* __restrict__ wl1,
    const float* __restrict__ bl1, float* __restrict__ h) {
    __shared__ float xs[8][IN_DIM];
    __shared__ float ms[8][IN_DIM];
    __shared__ float red[8][HIDDEN];
    __shared__ float rdeg[8];

    int base = blockIdx.x * 8;
    int tid = threadIdx.x;
    int wave = tid >> 6, lane = tid & 63;

    if (tid < 8) rdeg[tid] = 1.0f / fmaxf((float)degi[base + tid], 1.0f);
    for (int idx = tid; idx < 8 * IN_DIM; idx += 256) {
        int n = idx / IN_DIM, f = idx % IN_DIM;
        xs[n][f] = x[(base + n) * IN_DIM + f];  // root term: exact fp32
    }
    for (int r = 0; r < 2; ++r) {
        int n = wave * 2 + r;
        int node = base + n;
        int e0 = off[node], e1 = off[node + 1];
        float a0 = 0, a1 = 0, a2 = 0, a3 = 0;
        int e = e0;
        for (; e + 4 <= e1; e += 4) {
            int s0 = csr[e], s1 = csr[e + 1], s2 = csr[e + 2], s3 = csr[e + 3];
            if (lane < IN_DIM) {
                a0 += __bfloat162float(xb[s0 * IN_DIM + lane]);
                a1 += __bfloat162float(xb[s1 * IN_DIM + lane]);
                a2 += __bfloat162float(xb[s2 * IN_DIM + lane]);
                a3 += __bfloat162float(xb[s3 * IN_DIM + lane]);
            }
        }
        for (; e < e1; ++e)
            if (lane < IN_DIM) a0 += __bfloat162float(xb[csr[e] * IN_DIM + lane]);
        if (lane < IN_DIM) ms[n][lane] = (a0 + a1) + (a2 + a3);
    }
    __syncthreads();

    int j = tid;
    float accA[8] = {0}, accB[8] = {0}, accC[8] = {0};
    for (int f = 0; f < IN_DIM; ++f) {
        float wa = w1l[f * HIDDEN + j];
        float wb = w1r[f * HIDDEN + j];
        float wc = wl1[f * HIDDEN + j];
#pragma unroll
        for (int n = 0; n < 8; ++n) {
            accA[n] += ms[n][f] * wa;
            accB[n] += xs[n][f] * wb;
            accC[n] += xs[n][f] * wc;
        }
    }
    float bj = b1[j];
    float blj = bl1[j];
    float out1[8];
#pragma unroll
    for (int n = 0; n < 8; ++n) {
        out1[n] = accA[n] * rdeg[n] + bj + accB[n];
        red[n][j] = out1[n] * out1[n];
    }
    __syncthreads();
    for (int stride = 128; stride > 0; stride >>= 1) {
        if (j < stride) {
#pragma unroll
            for (int n = 0; n < 8; ++n) red[n][j] += red[n][j + stride];
        }
        __syncthreads();
    }
#pragma unroll
    for (int n = 0; n < 8; ++n) {
        float rn = 1.0f / fmaxf(sqrtf(red[n][0]), 1e-12f);
        float z = out1[n] * rn + accC[n] + blj;
        h[(base + n) * HIDDEN + j] = z > 0.0f ? z : expm1f(z);
    }
}

// ---------------- p = h @ w2_l  (bf16 output) ----------------
__global__ __launch_bounds__(128) void project2_r10(
    const float* __restrict__ h, const float* __restrict__ w2l,
    bf16* __restrict__ pb) {
    __shared__ float hs[8][HIDDEN];
    int base = blockIdx.x * 8;
    int tid = threadIdx.x;
    for (int idx = tid; idx < 8 * HIDDEN; idx += 128) {
        int n = idx >> 8, k = idx & 255;
        hs[n][k] = h[(base + n) * HIDDEN + k];
    }
    __syncthreads();
    int j = tid;
    if (j >= NCLS) return;
    float acc[8] = {0};
    for (int k = 0; k < HIDDEN; ++k) {
        float w = w2l[k * NCLS + j];
#pragma unroll
        for (int n = 0; n < 8; ++n) acc[n] += hs[n][k] * w;
    }
#pragma unroll
    for (int n = 0; n < 8; ++n)
        pb[(base + n) * PSTR + j] = __float2bfloat16(acc[n]);
}

// ---------------- layer 2 final (bf16 gather, 4-way MLP): 8 nodes, 128 thr --
__global__ __launch_bounds__(128) void layer2_r10(
    const float* __restrict__ h, const bf16* __restrict__ pb,
    const int* __restrict__ off, const int* __restrict__ csr,
    const int* __restrict__ degi,
    const float* __restrict__ b2, const float* __restrict__ w2r,
    const float* __restrict__ wl2, const float* __restrict__ bl2,
    float* __restrict__ out) {
    __shared__ float hs[8][HIDDEN];
    __shared__ float mp[8][NCLS];
    __shared__ float red[8][128];
    __shared__ float rdeg[8];

    int base = blockIdx.x * 8;
    int tid = threadIdx.x;
    if (tid < 8) rdeg[tid] = 1.0f / fmaxf((float)degi[base + tid], 1.0f);
    for (int idx = tid; idx < 8 * HIDDEN; idx += 128) {
        int n = idx >> 8, k = idx & 255;
        hs[n][k] = h[(base + n) * HIDDEN + k];
    }
    for (int n = 0; n < 8; ++n) {
        int node = base + n;
        int e0 = off[node], e1 = off[node + 1];
        if (tid < NCLS) {
            float a0 = 0, a1 = 0, a2 = 0, a3 = 0;
            int e = e0;
            for (; e + 4 <= e1; e += 4) {
                int s0 = csr[e], s1 = csr[e + 1];
                int s2 = csr[e + 2], s3 = csr[e + 3];
                a0 += __bfloat162float(pb[s0 * PSTR + tid]);
                a1 += __bfloat162float(pb[s1 * PSTR + tid]);
                a2 += __bfloat162float(pb[s2 * PSTR + tid]);
                a3 += __bfloat162float(pb[s3 * PSTR + tid]);
            }
            for (; e < e1; ++e) a0 += __bfloat162float(pb[csr[e] * PSTR + tid]);
            mp[n][tid] = (a0 + a1) + (a2 + a3);
        }
    }
    __syncthreads();

    int j = tid;
    float accB[8] = {0}, accC[8] = {0};
    if (j < NCLS) {
        for (int k = 0; k < HIDDEN; ++k) {
            float wb = w2r[k * NCLS + j];
            float wc = wl2[k * NCLS + j];
#pragma unroll
            for (int n = 0; n < 8; ++n) {
                accB[n] += hs[n][k] * wb;
                accC[n] += hs[n][k] * wc;
            }
        }
    }
    float bj = (j < NCLS) ? b2[j] : 0.0f;
    float blj = (j < NCLS) ? bl2[j] : 0.0f;
    float out2[8];
#pragma unroll
    for (int n = 0; n < 8; ++n) {
        out2[n] = (j < NCLS) ? (mp[n][j] * rdeg[n] + bj + accB[n]) : 0.0f;
        red[n][j] = out2[n] * out2[n];
    }
    __syncthreads();
    for (int stride = 64; stride > 0; stride >>= 1) {
        if (j < stride) {
#pragma unroll
            for (int n = 0; n < 8; ++n) red[n][j] += red[n][j + stride];
        }
        __syncthreads();
    }
    if (j < NCLS) {
#pragma unroll
        for (int n = 0; n < 8; ++n) {
            float rn = 1.0f / fmaxf(sqrtf(red[n][0]), 1e-12f);
            out[(base + n) * NCLS + j] = out2[n] * rn + accC[n] + blj;
        }
    }
}

extern "C" void kernel_launch(void* const* d_in, const int* in_sizes, int n_in,
                              void* d_out, int out_size, void* d_ws, size_t ws_size,
                              hipStream_t stream) {
    const float* x   = (const float*)d_in[0];
    const int*   ei  = (const int*)d_in[1];
    const float* w1l = (const float*)d_in[2];
    const float* b1  = (const float*)d_in[3];
    const float* w1r = (const float*)d_in[4];
    const float* wl1 = (const float*)d_in[5];
    const float* bl1 = (const float*)d_in[6];
    const float* w2l = (const float*)d_in[7];
    const float* b2  = (const float*)d_in[8];
    const float* w2r = (const float*)d_in[9];
    const float* wl2 = (const float*)d_in[10];
    const float* bl2 = (const float*)d_in[11];
    float* out = (float*)d_out;

    const int* src = ei;
    const int* dst = ei + N_EDGES;

    int*   wsI  = (int*)d_ws;
    float* wsF  = (float*)d_ws;
    int*   degi = wsI;
    int*   off  = wsI + OFF_OFF;
    int*   cur  = wsI + OFF_CUR;
    int*   csr  = wsI + OFF_CSR;
    float* h    = wsF + OFF_H;
    bf16*  pb   = (bf16*)(wsF + OFF_PB);
    bf16*  xb   = (bf16*)(wsF + OFF_XB);

    hipMemsetAsync(degi, 0, (size_t)N_NODES * sizeof(int), stream);

    convx_r10<<<(N_NODES * IN_DIM + 255) / 256, 256, 0, stream>>>(x, xb);
    degcount_r10<<<(N_EDGES + 255) / 256, 256, 0, stream>>>(dst, degi);
    scan_r10<<<1, 256, 0, stream>>>(degi, off, cur);
    csrfill_r10<<<(N_EDGES + 255) / 256, 256, 0, stream>>>(src, dst, cur, csr);

    layer1_r10<<<N_NODES / 8, 256, 0, stream>>>(x, xb, off, csr, degi,
                                                w1l, b1, w1r, wl1, bl1, h);
    project2_r10<<<N_NODES / 8, 128, 0, stream>>>(h, w2l, pb);
    layer2_r10<<<N_NODES / 8, 128, 0, stream>>>(h, pb, off, csr, degi,
                                                b2, w2r, wl2, bl2, out);
}